// Round 1
// baseline (114.118 us; speedup 1.0000x reference)
//
#include <hip/hip_runtime.h>

#define NSYS 64
#define NAT  1000
#define NTOT (NSYS * NAT)          // 64000
#define MP   2200000               // MAX_PAIRS
#define CUT2 25.0f                 // cutoff^2
#define PADV 64000.0f              // padding_value = n
#define SCAN_BLOCKS 250            // 250 * 256 == 64000 exactly
#define CAP  104                   // per-row record capacity (max ~57 expected)
#define EB   512                   // eval blocks: 2 per CU, one round
#define LCN  1152                  // LDS atoms incl. tail overrun (j <= 1062)
#define NROWS 512                  // rows staged per emit block
#define POSB  4096                 // output positions per emit block
#define EMITB ((MP + POSB - 1) / POSB)   // 538

__device__ __forceinline__ float dist2f(float xi, float yi, float zi,
                                        float xj, float yj, float zj) {
    float dx = xi - xj, dy = yi - yj, dz = zi - zj;
    return fmaf(dz, dz, fmaf(dy, dy, dx * dx));
}

// popcount of mask over lanes strictly below me (2 VALU: v_mbcnt_lo/hi)
__device__ __forceinline__ int mbcnt(unsigned long long m) {
    unsigned lo = __builtin_amdgcn_mbcnt_lo((unsigned)m, 0u);
    return (int)__builtin_amdgcn_mbcnt_hi((unsigned)(m >> 32), lo);
}

// Emit one ballot group's kept pair (ascending-j order preserved).
__device__ __forceinline__ int emit_group(uint2* __restrict__ q, int running,
                                          bool k, int j, int r, float d,
                                          unsigned long long m) {
    if (k) {
        int rank = running + mbcnt(m);
        if (rank < CAP)
            q[rank] = make_uint2((unsigned)(j - r), __float_as_uint(d));
    }
    return running + (int)__popcll(m);
}

// Persistent eval: block b = (system s = b>>3, stripe = b&7). Stage system
// coords once as float4 SoA in LDS; wave W = stripe*16+w handles rows
// r = (t odd ? 127-W : W) + 128t (alternating stripe balances load).
// Inner loop unrolled 4x (stride 256): 4 independent ds_read_b128 in flight.
// Row base readfirstlane'd -> SGPR-base stores (saves 64b VGPR addressing).
__global__ __launch_bounds__(1024) void k_eval(const float* __restrict__ coords,
                                               int* __restrict__ counts,
                                               uint2* __restrict__ qbuf) {
    __shared__ float4 lc[LCN];
    int s      = blockIdx.x >> 3;
    int stripe = blockIdx.x & 7;
    const float* cs = coords + s * (NAT * 3);
    for (int a = threadIdx.x; a < LCN; a += 1024)
        lc[a] = (a < NAT)
              ? make_float4(cs[3 * a], cs[3 * a + 1], cs[3 * a + 2], 0.0f)
              : make_float4(1.0e30f, 1.0e30f, 1.0e30f, 0.0f);
    __syncthreads();
    int w    = threadIdx.x >> 6;
    int lane = threadIdx.x & 63;
    int W    = stripe * 16 + w;
    for (int t = 0;; t++) {
        int r = ((t & 1) ? (127 - W) : W) + (t << 7);
        if (r >= NAT) { if (((t & 1) ? W : (127 - W)) + (t << 7) >= NAT) break; else continue; }
        float4 ci = lc[r];
        int grow = __builtin_amdgcn_readfirstlane(s * NAT + r);   // wave-uniform
        uint2* q = qbuf + (size_t)grow * CAP;
        int running = 0;
        int jb = r + 1;
        // full 256-wide iterations: all four j-groups < NAT guaranteed
        for (; jb + 255 < NAT; jb += 256) {
            int j = jb + lane;
            float4 c0 = lc[j];
            float4 c1 = lc[j + 64];
            float4 c2 = lc[j + 128];
            float4 c3 = lc[j + 192];
            float d0 = dist2f(ci.x, ci.y, ci.z, c0.x, c0.y, c0.z);
            float d1 = dist2f(ci.x, ci.y, ci.z, c1.x, c1.y, c1.z);
            float d2 = dist2f(ci.x, ci.y, ci.z, c2.x, c2.y, c2.z);
            float d3 = dist2f(ci.x, ci.y, ci.z, c3.x, c3.y, c3.z);
            bool k0 = d0 < CUT2;
            bool k1 = d1 < CUT2;
            bool k2 = d2 < CUT2;
            bool k3 = d3 < CUT2;
            unsigned long long m0 = __ballot(k0);
            unsigned long long m1 = __ballot(k1);
            unsigned long long m2 = __ballot(k2);
            unsigned long long m3 = __ballot(k3);
            running = emit_group(q, running, k0, j,       r, d0, m0);
            running = emit_group(q, running, k1, j + 64,  r, d1, m1);
            running = emit_group(q, running, k2, j + 128, r, d2, m2);
            running = emit_group(q, running, k3, j + 192, r, d3, m3);
        }
        // tail: <=4 checked 64-wide iterations
        for (; jb < NAT; jb += 64) {
            int j = jb + lane;
            float4 c0 = lc[j];
            float d0 = dist2f(ci.x, ci.y, ci.z, c0.x, c0.y, c0.z);
            bool k0 = (j < NAT) && (d0 < CUT2);
            unsigned long long m0 = __ballot(k0);
            running = emit_group(q, running, k0, j, r, d0, m0);
        }
        if (lane == 0) counts[grow] = running;
    }
}

// Level-1 scan: 250 blocks x 256 rows -> block-exclusive offs[] + block sums.
// Shuffle-based wave scan (no LDS ping-pong barriers).
__global__ __launch_bounds__(256) void k_scan_a(const int* __restrict__ counts,
                                                int* __restrict__ offs,
                                                int* __restrict__ bsum) {
    __shared__ int wsum[4];
    int t = threadIdx.x, lane = t & 63, wid = t >> 6;
    int g = blockIdx.x * 256 + t;
    int v = counts[g];
    int x = v;
#pragma unroll
    for (int off = 1; off < 64; off <<= 1) {
        int u = __shfl_up(x, off);
        if (lane >= off) x += u;
    }
    if (lane == 63) wsum[wid] = x;
    __syncthreads();
    int base = 0;
    if (wid > 0) base += wsum[0];
    if (wid > 1) base += wsum[1];
    if (wid > 2) base += wsum[2];
    offs[g] = base + x - v;                       // block-exclusive prefix
    if (t == 255) bsum[blockIdx.x] = base + x;    // block total
}

// Level-2 scan ONCE + per-emit-block r0 binary searches in parallel.
// Replaces the redundant 256-scan + serial global search in every emit block.
__global__ __launch_bounds__(1024) void k_scan_b(const int* __restrict__ offs,
                                                 const int* __restrict__ bsum,
                                                 int* __restrict__ bpre,
                                                 int* __restrict__ r0g,
                                                 int* __restrict__ totp,
                                                 float* __restrict__ out) {
    __shared__ int bexc[256];
    __shared__ int wsum[4];
    __shared__ int sh_tot;
    int t = threadIdx.x, lane = t & 63, wid = t >> 6;
    int v = 0, x = 0;
    if (t < 256) {
        v = (t < SCAN_BLOCKS) ? bsum[t] : 0;
        x = v;
#pragma unroll
        for (int off = 1; off < 64; off <<= 1) {
            int u = __shfl_up(x, off);
            if (lane >= off) x += u;
        }
        if (lane == 63) wsum[wid] = x;
    }
    __syncthreads();
    if (t < 256) {
        int base = 0;
        if (wid > 0) base += wsum[0];
        if (wid > 1) base += wsum[1];
        if (wid > 2) base += wsum[2];
        int excl = base + x - v;
        bexc[t] = excl;
        bpre[t] = excl;
        if (t == 255) {
            int tot = base + x;
            sh_tot = tot;
            totp[0] = tot;
            out[6 * MP] = (float)tot;             // npairs
        }
    }
    __syncthreads();
    int total = sh_tot;
    // 538 independent searches, one per emit block: largest r, goff(r) <= p0
    for (int eb = t; eb < EMITB; eb += 1024) {
        int p0 = eb * POSB;
        int lo = 0, hi = NTOT;
        while (lo < hi) {
            int mid = (lo + hi + 1) >> 1;
            int gg = (mid < NTOT) ? offs[mid] + bexc[mid >> 8] : total;
            if (gg <= p0) lo = mid; else hi = mid - 1;
        }
        r0g[eb] = lo;
    }
}

// Position-indexed emit + pad, fully coalesced (proven R7 structure).
// Prologue slimmed: r0/total are broadcast loads; single barrier.
// Out layout: [0)src [MP)dst [2MP)dst [3MP)src [4MP)d12 [5MP)d12 [6MP]npairs
__global__ __launch_bounds__(1024) void k_emit(const int* __restrict__ offs,
                                               const int* __restrict__ bpre,
                                               const int* __restrict__ r0g,
                                               const int* __restrict__ totp,
                                               const uint2* __restrict__ qbuf,
                                               float* __restrict__ out) {
    __shared__ int lgoff[NROWS + 1];
    int t = threadIdx.x;
    int r0 = r0g[blockIdx.x];                     // same-address broadcast, L2-hot
    int total = totp[0];
    if (t <= NROWS) {
        int r = r0 + t;
        lgoff[t] = (r < NTOT) ? offs[r] + bpre[r >> 8] : total;
    }
    __syncthreads();

    int p0 = blockIdx.x * POSB;
    int valid = total < MP ? total : MP;

    int p4 = p0 + t * 4;
    if (p4 >= MP) return;
    int k = 0;
    for (int step = 256; step; step >>= 1) {
        int nk = k + step;
        if (nk <= NROWS - 1 && lgoff[nk] <= p4) k = nk;
    }
    float fs[4], fd[4], dd[4];
#pragma unroll
    for (int e = 0; e < 4; e++) {
        int p = p4 + e;
        if (p < valid) {
            while (k < NROWS - 1 && lgoff[k + 1] <= p) k++;
            int row = r0 + k;
            int local = p - lgoff[k];
            if (local > CAP - 1) local = CAP - 1;    // count>CAP guard (P~0)
            uint2 rec = qbuf[(size_t)row * CAP + local];
            fs[e] = (float)row;
            fd[e] = (float)(row + (int)rec.x);
            dd[e] = __uint_as_float(rec.y);
        } else {
            fs[e] = PADV; fd[e] = PADV; dd[e] = CUT2;
        }
    }
    if (p4 + 4 <= MP) {
        float4 vs = {fs[0], fs[1], fs[2], fs[3]};
        float4 vd = {fd[0], fd[1], fd[2], fd[3]};
        float4 vv = {dd[0], dd[1], dd[2], dd[3]};
        *(float4*)(out + p4)          = vs;
        *(float4*)(out + MP + p4)     = vd;
        *(float4*)(out + 2 * MP + p4) = vd;
        *(float4*)(out + 3 * MP + p4) = vs;
        *(float4*)(out + 4 * MP + p4) = vv;
        *(float4*)(out + 5 * MP + p4) = vv;
    } else {
#pragma unroll
        for (int e = 0; e < 4; e++) {
            int p = p4 + e;
            if (p < MP) {
                out[p]          = fs[e];
                out[MP + p]     = fd[e];
                out[2 * MP + p] = fd[e];
                out[3 * MP + p] = fs[e];
                out[4 * MP + p] = dd[e];
                out[5 * MP + p] = dd[e];
            }
        }
    }
}

extern "C" void kernel_launch(void* const* d_in, const int* in_sizes, int n_in,
                              void* d_out, int out_size, void* d_ws, size_t ws_size,
                              hipStream_t stream) {
    const float* coords = (const float*)d_in[0];
    float* out = (float*)d_out;

    // Workspace: counts[64000] | offs[64000] | bsum[256] | bpre[256] |
    //            r0g[544] | totp[8] | qbuf (8B-aligned: 129064 ints = 516256 B)
    int*   counts = (int*)d_ws;
    int*   offs   = counts + NTOT;
    int*   bsum   = offs + NTOT;
    int*   bpre   = bsum + 256;
    int*   r0g    = bpre + 256;
    int*   totp   = r0g + 544;
    uint2* qbuf   = (uint2*)(totp + 8);

    k_eval<<<EB, 1024, 0, stream>>>(coords, counts, qbuf);
    k_scan_a<<<SCAN_BLOCKS, 256, 0, stream>>>(counts, offs, bsum);
    k_scan_b<<<1, 1024, 0, stream>>>(offs, bsum, bpre, r0g, totp, out);
    k_emit<<<EMITB, 1024, 0, stream>>>(offs, bpre, r0g, totp, qbuf, out);
}

// Round 2
// 108.317 us; speedup vs baseline: 1.0536x; 1.0536x over previous
//
#include <hip/hip_runtime.h>

#define NSYS 64
#define NAT  1000
#define NTOT (NSYS * NAT)          // 64000
#define MP   2200000               // MAX_PAIRS
#define CUT2 25.0f                 // cutoff^2
#define PADV 64000.0f              // padding_value = n
#define SCAN_BLOCKS 250            // 250 * 256 == 64000 exactly
#define CAP  104                   // per-row record capacity (max ~57 expected)
#define EB   512                   // eval blocks: 2 per CU, one round
#define LCN  1152                  // LDS atoms incl. tail overrun (j <= 1062)
#define NROWS 512                  // rows staged per emit block
#define POSB  4096                 // output positions per emit block

__device__ __forceinline__ float dist2f(float xi, float yi, float zi,
                                        float xj, float yj, float zj) {
    float dx = xi - xj, dy = yi - yj, dz = zi - zj;
    return fmaf(dz, dz, fmaf(dy, dy, dx * dx));
}

// popcount of mask over lanes strictly below me (2 VALU: v_mbcnt_lo/hi)
__device__ __forceinline__ int mbcnt(unsigned long long m) {
    unsigned lo = __builtin_amdgcn_mbcnt_lo((unsigned)m, 0u);
    return (int)__builtin_amdgcn_mbcnt_hi((unsigned)(m >> 32), lo);
}

// Emit one ballot group's kept pair (ascending-j order preserved).
__device__ __forceinline__ int emit_group(uint2* __restrict__ q, int running,
                                          bool k, int j, int r, float d,
                                          unsigned long long m) {
    if (k) {
        int rank = running + mbcnt(m);
        if (rank < CAP)
            q[rank] = make_uint2((unsigned)(j - r), __float_as_uint(d));
    }
    return running + (int)__popcll(m);
}

// Persistent eval, QUAD-ROW version: block b = (system s = b>>3, stripe = b&7).
// Stage system coords once as float4 SoA in LDS. Wave W = stripe*16+w owns
// row-quads Q = W (t=0) and Q = 255-W (t=1, valid when <=249): rows 4Q..4Q+3
// held in registers, so every ds_read_b128 of lc[j] is reused for 4 distance
// tests -> 4x less LDS traffic (was the per-CU bottleneck at ~12cyc/b128).
// Pairing (W, 255-W) balances cost to ~978 j-iters/wave (~2% imbalance).
// Intra-quad triangle is folded into the first 64-wide group via per-row
// (j > r) masks, keeping exact ascending-j ballot order per row.
__global__ __launch_bounds__(1024) void k_eval(const float* __restrict__ coords,
                                               int* __restrict__ counts,
                                               uint2* __restrict__ qbuf) {
    __shared__ float4 lc[LCN];
    int s      = blockIdx.x >> 3;
    int stripe = blockIdx.x & 7;
    const float* cs = coords + s * (NAT * 3);
    for (int a = threadIdx.x; a < LCN; a += 1024)
        lc[a] = (a < NAT)
              ? make_float4(cs[3 * a], cs[3 * a + 1], cs[3 * a + 2], 0.0f)
              : make_float4(1.0e30f, 1.0e30f, 1.0e30f, 0.0f);
    __syncthreads();
    int w    = threadIdx.x >> 6;
    int lane = threadIdx.x & 63;
    int W    = stripe * 16 + w;
#pragma unroll
    for (int t = 0; t < 2; t++) {
        int Q = t ? (255 - W) : W;
        if (Q > 249) continue;                       // only W<6 skips at t=1
        int r0 = Q * 4;
        float4 a0 = lc[r0];
        float4 a1 = lc[r0 + 1];
        float4 a2 = lc[r0 + 2];
        float4 a3 = lc[r0 + 3];
        int gb = __builtin_amdgcn_readfirstlane(s * NAT + r0);  // wave-uniform
        uint2* q0 = qbuf + (size_t)gb * CAP;
        uint2* q1 = q0 + CAP;
        uint2* q2 = q1 + CAP;
        uint2* q3 = q2 + CAP;
        int run0 = 0, run1 = 0, run2 = 0, run3 = 0;
        // Group A: j in [r0+1, r0+64]; per-row j>r masks fold the intra-quad
        // triangle; j<NAT check needed only for Q=249 but cheap to keep.
        {
            int j = r0 + 1 + lane;
            float4 c = lc[j];
            float d0 = dist2f(a0.x, a0.y, a0.z, c.x, c.y, c.z);
            float d1 = dist2f(a1.x, a1.y, a1.z, c.x, c.y, c.z);
            float d2 = dist2f(a2.x, a2.y, a2.z, c.x, c.y, c.z);
            float d3 = dist2f(a3.x, a3.y, a3.z, c.x, c.y, c.z);
            bool in = j < NAT;
            bool k0 = in && (d0 < CUT2);
            bool k1 = in && (j > r0 + 1) && (d1 < CUT2);
            bool k2 = in && (j > r0 + 2) && (d2 < CUT2);
            bool k3 = in && (j > r0 + 3) && (d3 < CUT2);
            unsigned long long m0 = __ballot(k0);
            unsigned long long m1 = __ballot(k1);
            unsigned long long m2 = __ballot(k2);
            unsigned long long m3 = __ballot(k3);
            run0 = emit_group(q0, run0, k0, j, r0,     d0, m0);
            run1 = emit_group(q1, run1, k1, j, r0 + 1, d1, m1);
            run2 = emit_group(q2, run2, k2, j, r0 + 2, d2, m2);
            run3 = emit_group(q3, run3, k3, j, r0 + 3, d3, m3);
        }
        int jb = r0 + 65;
        // unchecked 128-wide iterations: 2 ds_read_b128 in flight, each
        // feeding 4 rows' distance tests
        for (; jb + 127 < NAT; jb += 128) {
            int j = jb + lane;
            float4 c0 = lc[j];
            float4 c1 = lc[j + 64];
            float d00 = dist2f(a0.x, a0.y, a0.z, c0.x, c0.y, c0.z);
            float d10 = dist2f(a1.x, a1.y, a1.z, c0.x, c0.y, c0.z);
            float d20 = dist2f(a2.x, a2.y, a2.z, c0.x, c0.y, c0.z);
            float d30 = dist2f(a3.x, a3.y, a3.z, c0.x, c0.y, c0.z);
            bool k00 = d00 < CUT2;
            bool k10 = d10 < CUT2;
            bool k20 = d20 < CUT2;
            bool k30 = d30 < CUT2;
            unsigned long long m00 = __ballot(k00);
            unsigned long long m10 = __ballot(k10);
            unsigned long long m20 = __ballot(k20);
            unsigned long long m30 = __ballot(k30);
            run0 = emit_group(q0, run0, k00, j, r0,     d00, m00);
            run1 = emit_group(q1, run1, k10, j, r0 + 1, d10, m10);
            run2 = emit_group(q2, run2, k20, j, r0 + 2, d20, m20);
            run3 = emit_group(q3, run3, k30, j, r0 + 3, d30, m30);
            float d01 = dist2f(a0.x, a0.y, a0.z, c1.x, c1.y, c1.z);
            float d11 = dist2f(a1.x, a1.y, a1.z, c1.x, c1.y, c1.z);
            float d21 = dist2f(a2.x, a2.y, a2.z, c1.x, c1.y, c1.z);
            float d31 = dist2f(a3.x, a3.y, a3.z, c1.x, c1.y, c1.z);
            bool k01 = d01 < CUT2;
            bool k11 = d11 < CUT2;
            bool k21 = d21 < CUT2;
            bool k31 = d31 < CUT2;
            unsigned long long m01 = __ballot(k01);
            unsigned long long m11 = __ballot(k11);
            unsigned long long m21 = __ballot(k21);
            unsigned long long m31 = __ballot(k31);
            run0 = emit_group(q0, run0, k01, j + 64, r0,     d01, m01);
            run1 = emit_group(q1, run1, k11, j + 64, r0 + 1, d11, m11);
            run2 = emit_group(q2, run2, k21, j + 64, r0 + 2, d21, m21);
            run3 = emit_group(q3, run3, k31, j + 64, r0 + 3, d31, m31);
        }
        // checked 64-wide tail (<=2 iterations)
        for (; jb < NAT; jb += 64) {
            int j = jb + lane;
            float4 c = lc[j];
            float d0 = dist2f(a0.x, a0.y, a0.z, c.x, c.y, c.z);
            float d1 = dist2f(a1.x, a1.y, a1.z, c.x, c.y, c.z);
            float d2 = dist2f(a2.x, a2.y, a2.z, c.x, c.y, c.z);
            float d3 = dist2f(a3.x, a3.y, a3.z, c.x, c.y, c.z);
            bool in = j < NAT;
            bool k0 = in && (d0 < CUT2);
            bool k1 = in && (d1 < CUT2);
            bool k2 = in && (d2 < CUT2);
            bool k3 = in && (d3 < CUT2);
            unsigned long long m0 = __ballot(k0);
            unsigned long long m1 = __ballot(k1);
            unsigned long long m2 = __ballot(k2);
            unsigned long long m3 = __ballot(k3);
            run0 = emit_group(q0, run0, k0, j, r0,     d0, m0);
            run1 = emit_group(q1, run1, k1, j, r0 + 1, d1, m1);
            run2 = emit_group(q2, run2, k2, j, r0 + 2, d2, m2);
            run3 = emit_group(q3, run3, k3, j, r0 + 3, d3, m3);
        }
        if (lane == 0)
            *(int4*)(counts + gb) = make_int4(run0, run1, run2, run3);
    }
}

// Level-1 scan: 250 blocks x 256 rows -> block-exclusive offs[] + block sums.
// Shuffle-based wave scan (no LDS ping-pong barriers).
__global__ __launch_bounds__(256) void k_scan_a(const int* __restrict__ counts,
                                                int* __restrict__ offs,
                                                int* __restrict__ bsum) {
    __shared__ int wsum[4];
    int t = threadIdx.x, lane = t & 63, wid = t >> 6;
    int g = blockIdx.x * 256 + t;
    int v = counts[g];
    int x = v;
#pragma unroll
    for (int off = 1; off < 64; off <<= 1) {
        int u = __shfl_up(x, off);
        if (lane >= off) x += u;
    }
    if (lane == 63) wsum[wid] = x;
    __syncthreads();
    int base = 0;
    if (wid > 0) base += wsum[0];
    if (wid > 1) base += wsum[1];
    if (wid > 2) base += wsum[2];
    offs[g] = base + x - v;                       // block-exclusive prefix
    if (t == 255) bsum[blockIdx.x] = base + x;    // block total
}

// Position-indexed emit + pad, fully coalesced (proven R7/R0 structure:
// self-contained level-2 scan + serial search are hidden under 538-block
// parallelism; a separate scan kernel measured WORSE by ~3us of launch).
// Out layout: [0)src [MP)dst [2MP)dst [3MP)src [4MP)d12 [5MP)d12 [6MP]npairs
__global__ __launch_bounds__(1024) void k_emit(const int* __restrict__ offs,
                                               const int* __restrict__ bsum,
                                               const uint2* __restrict__ qbuf,
                                               float* __restrict__ out) {
    __shared__ int bpre[256];
    __shared__ int lgoff[NROWS + 1];
    __shared__ int sh_r0, sh_tot;
    int t = threadIdx.x;
    int v = 0;
    if (t < 256) {
        v = (t < SCAN_BLOCKS) ? bsum[t] : 0;
        bpre[t] = v;
    }
    __syncthreads();
    for (int off = 1; off < 256; off <<= 1) {
        int u = 0;
        if (t < 256 && t >= off) u = bpre[t - off];
        __syncthreads();
        if (t < 256) bpre[t] += u;
        __syncthreads();
    }
    int incl = (t < 256) ? bpre[t] : 0;
    __syncthreads();
    if (t < 256) bpre[t] = incl - v;                 // exclusive prefix
    if (t == 255) sh_tot = incl;                     // grand total
    __syncthreads();
    int total = sh_tot;

    int p0 = blockIdx.x * POSB;
    if (t == 0) {
        int lo = 0, hi = NTOT;                       // largest r: goff(r) <= p0
        while (lo < hi) {
            int mid = (lo + hi + 1) >> 1;
            int g = (mid < NTOT) ? offs[mid] + bpre[mid >> 8] : total;
            if (g <= p0) lo = mid; else hi = mid - 1;
        }
        sh_r0 = lo;
    }
    __syncthreads();
    int r0 = sh_r0;
    if (t <= NROWS) {
        int r = r0 + t;
        lgoff[t] = (r < NTOT) ? offs[r] + bpre[r >> 8] : total;
    }
    __syncthreads();

    if (blockIdx.x == 0 && t == 0) out[6 * MP] = (float)total;  // npairs
    int valid = total < MP ? total : MP;

    int p4 = p0 + t * 4;
    if (p4 >= MP) return;
    int k = 0;
    for (int step = 256; step; step >>= 1) {
        int nk = k + step;
        if (nk <= NROWS - 1 && lgoff[nk] <= p4) k = nk;
    }
    float fs[4], fd[4], dd[4];
#pragma unroll
    for (int e = 0; e < 4; e++) {
        int p = p4 + e;
        if (p < valid) {
            while (k < NROWS - 1 && lgoff[k + 1] <= p) k++;
            int row = r0 + k;
            int local = p - lgoff[k];
            if (local > CAP - 1) local = CAP - 1;    // count>CAP guard (P~0)
            uint2 rec = qbuf[(size_t)row * CAP + local];
            fs[e] = (float)row;
            fd[e] = (float)(row + (int)rec.x);
            dd[e] = __uint_as_float(rec.y);
        } else {
            fs[e] = PADV; fd[e] = PADV; dd[e] = CUT2;
        }
    }
    if (p4 + 4 <= MP) {
        float4 vs = {fs[0], fs[1], fs[2], fs[3]};
        float4 vd = {fd[0], fd[1], fd[2], fd[3]};
        float4 vv = {dd[0], dd[1], dd[2], dd[3]};
        *(float4*)(out + p4)          = vs;
        *(float4*)(out + MP + p4)     = vd;
        *(float4*)(out + 2 * MP + p4) = vd;
        *(float4*)(out + 3 * MP + p4) = vs;
        *(float4*)(out + 4 * MP + p4) = vv;
        *(float4*)(out + 5 * MP + p4) = vv;
    } else {
#pragma unroll
        for (int e = 0; e < 4; e++) {
            int p = p4 + e;
            if (p < MP) {
                out[p]          = fs[e];
                out[MP + p]     = fd[e];
                out[2 * MP + p] = fd[e];
                out[3 * MP + p] = fs[e];
                out[4 * MP + p] = dd[e];
                out[5 * MP + p] = dd[e];
            }
        }
    }
}

extern "C" void kernel_launch(void* const* d_in, const int* in_sizes, int n_in,
                              void* d_out, int out_size, void* d_ws, size_t ws_size,
                              hipStream_t stream) {
    const float* coords = (const float*)d_in[0];
    float* out = (float*)d_out;

    // Workspace: counts[64000] | offs[64000] | bsum[256] | qbuf (8B-aligned)
    int*   counts = (int*)d_ws;
    int*   offs   = counts + NTOT;
    int*   bsum   = offs + NTOT;
    uint2* qbuf   = (uint2*)(bsum + 256);

    int emit_blocks = (MP + POSB - 1) / POSB;        // 538
    k_eval<<<EB, 1024, 0, stream>>>(coords, counts, qbuf);
    k_scan_a<<<SCAN_BLOCKS, 256, 0, stream>>>(counts, offs, bsum);
    k_emit<<<emit_blocks, 1024, 0, stream>>>(offs, bsum, qbuf, out);
}

// Round 3
// 106.277 us; speedup vs baseline: 1.0738x; 1.0192x over previous
//
#include <hip/hip_runtime.h>

#define NSYS 64
#define NAT  1000
#define NTOT (NSYS * NAT)          // 64000
#define MP   2200000               // MAX_PAIRS
#define CUT2 25.0f                 // cutoff^2
#define PADV 64000.0f              // padding_value = n
#define SCAN_BLOCKS 250            // 250 * 256 == 64000 exactly
#define CAP  104                   // per-row record capacity (max ~57 expected)
#define EB   512                   // eval blocks: 2 per CU, one round
#define LCN  1216                  // LDS atoms incl. sentinel overrun (j <= 1190)
#define NROWS 512                  // rows staged per emit block
#define POSB  4096                 // output positions per emit block

__device__ __forceinline__ float dist2f(float xi, float yi, float zi,
                                        float xj, float yj, float zj) {
    float dx = xi - xj, dy = yi - yj, dz = zi - zj;
    return fmaf(dz, dz, fmaf(dy, dy, dx * dx));
}

// popcount of mask over lanes strictly below me (2 VALU: v_mbcnt_lo/hi)
__device__ __forceinline__ int mbcnt(unsigned long long m) {
    unsigned lo = __builtin_amdgcn_mbcnt_lo((unsigned)m, 0u);
    return (int)__builtin_amdgcn_mbcnt_hi((unsigned)(m >> 32), lo);
}

// Emit one ballot group's kept pair as a u16 (j-r) record; d2 is recomputed
// in k_emit from coords (bit-identical fmaf expression) -> 4x less qbuf HBM.
__device__ __forceinline__ int emit_group(unsigned short* __restrict__ q,
                                          int running, bool k, int dj,
                                          unsigned long long m) {
    if (k) {
        int rank = running + mbcnt(m);
        if (rank < CAP)
            q[rank] = (unsigned short)dj;
    }
    return running + (int)__popcll(m);
}

// Persistent eval, QUAD-ROW: block b = (system s = b>>3, stripe = b&7).
// Stage system coords once as float4 SoA in LDS (sentinel 1e30 past NAT: its
// distances are ~1e60 > CUT2, so NO j<NAT checks or checked tail needed;
// LCN=1216 covers max touched j=1190). Wave W = stripe*16+w owns row-quads
// Q = W and Q = 255-W (<=249): rows 4Q..4Q+3 in registers, every
// ds_read_b128 of lc[j] reused for 4 distance tests (4x less LDS traffic).
// Intra-quad triangle folded into first 64-group via per-row j>r masks,
// keeping exact ascending-j ballot order per row.
__global__ __launch_bounds__(1024) void k_eval(const float* __restrict__ coords,
                                               int* __restrict__ counts,
                                               unsigned short* __restrict__ qbuf) {
    __shared__ float4 lc[LCN];
    int s      = blockIdx.x >> 3;
    int stripe = blockIdx.x & 7;
    const float* cs = coords + s * (NAT * 3);
    for (int a = threadIdx.x; a < LCN; a += 1024)
        lc[a] = (a < NAT)
              ? make_float4(cs[3 * a], cs[3 * a + 1], cs[3 * a + 2], 0.0f)
              : make_float4(1.0e30f, 1.0e30f, 1.0e30f, 0.0f);
    __syncthreads();
    int w    = threadIdx.x >> 6;
    int lane = threadIdx.x & 63;
    int W    = stripe * 16 + w;
#pragma unroll
    for (int t = 0; t < 2; t++) {
        int Q = t ? (255 - W) : W;
        if (Q > 249) continue;                       // only W<6 skips at t=1
        int r0 = Q * 4;
        float4 a0 = lc[r0];
        float4 a1 = lc[r0 + 1];
        float4 a2 = lc[r0 + 2];
        float4 a3 = lc[r0 + 3];
        int gb = __builtin_amdgcn_readfirstlane(s * NAT + r0);  // wave-uniform
        unsigned short* q0 = qbuf + (size_t)gb * CAP;
        unsigned short* q1 = q0 + CAP;
        unsigned short* q2 = q1 + CAP;
        unsigned short* q3 = q2 + CAP;
        int run0 = 0, run1 = 0, run2 = 0, run3 = 0;
        // Group A: j in [r0+1, r0+64]; per-row j>r masks fold the triangle.
        {
            int j = r0 + 1 + lane;
            float4 c = lc[j];
            float d0 = dist2f(a0.x, a0.y, a0.z, c.x, c.y, c.z);
            float d1 = dist2f(a1.x, a1.y, a1.z, c.x, c.y, c.z);
            float d2 = dist2f(a2.x, a2.y, a2.z, c.x, c.y, c.z);
            float d3 = dist2f(a3.x, a3.y, a3.z, c.x, c.y, c.z);
            bool k0 = d0 < CUT2;
            bool k1 = (lane > 0) && (d1 < CUT2);
            bool k2 = (lane > 1) && (d2 < CUT2);
            bool k3 = (lane > 2) && (d3 < CUT2);
            unsigned long long m0 = __ballot(k0);
            unsigned long long m1 = __ballot(k1);
            unsigned long long m2 = __ballot(k2);
            unsigned long long m3 = __ballot(k3);
            run0 = emit_group(q0, run0, k0, j - r0,     m0);
            run1 = emit_group(q1, run1, k1, j - r0 - 1, m1);
            run2 = emit_group(q2, run2, k2, j - r0 - 2, m2);
            run3 = emit_group(q3, run3, k3, j - r0 - 3, m3);
        }
        // unchecked 128-wide iterations (sentinel handles j >= NAT)
        for (int jb = r0 + 65; jb < NAT; jb += 128) {
            int j = jb + lane;
            float4 c0 = lc[j];
            float4 c1 = lc[j + 64];
            float d00 = dist2f(a0.x, a0.y, a0.z, c0.x, c0.y, c0.z);
            float d10 = dist2f(a1.x, a1.y, a1.z, c0.x, c0.y, c0.z);
            float d20 = dist2f(a2.x, a2.y, a2.z, c0.x, c0.y, c0.z);
            float d30 = dist2f(a3.x, a3.y, a3.z, c0.x, c0.y, c0.z);
            bool k00 = d00 < CUT2;
            bool k10 = d10 < CUT2;
            bool k20 = d20 < CUT2;
            bool k30 = d30 < CUT2;
            unsigned long long m00 = __ballot(k00);
            unsigned long long m10 = __ballot(k10);
            unsigned long long m20 = __ballot(k20);
            unsigned long long m30 = __ballot(k30);
            run0 = emit_group(q0, run0, k00, j - r0,     m00);
            run1 = emit_group(q1, run1, k10, j - r0 - 1, m10);
            run2 = emit_group(q2, run2, k20, j - r0 - 2, m20);
            run3 = emit_group(q3, run3, k30, j - r0 - 3, m30);
            float d01 = dist2f(a0.x, a0.y, a0.z, c1.x, c1.y, c1.z);
            float d11 = dist2f(a1.x, a1.y, a1.z, c1.x, c1.y, c1.z);
            float d21 = dist2f(a2.x, a2.y, a2.z, c1.x, c1.y, c1.z);
            float d31 = dist2f(a3.x, a3.y, a3.z, c1.x, c1.y, c1.z);
            bool k01 = d01 < CUT2;
            bool k11 = d11 < CUT2;
            bool k21 = d21 < CUT2;
            bool k31 = d31 < CUT2;
            unsigned long long m01 = __ballot(k01);
            unsigned long long m11 = __ballot(k11);
            unsigned long long m21 = __ballot(k21);
            unsigned long long m31 = __ballot(k31);
            run0 = emit_group(q0, run0, k01, j + 64 - r0,     m01);
            run1 = emit_group(q1, run1, k11, j + 64 - r0 - 1, m11);
            run2 = emit_group(q2, run2, k21, j + 64 - r0 - 2, m21);
            run3 = emit_group(q3, run3, k31, j + 64 - r0 - 3, m31);
        }
        if (lane == 0)
            *(int4*)(counts + gb) = make_int4(run0, run1, run2, run3);
    }
}

// Level-1 scan: 250 blocks x 256 rows -> block-exclusive offs[] + block sums.
// Shuffle-based wave scan (no LDS ping-pong barriers).
__global__ __launch_bounds__(256) void k_scan_a(const int* __restrict__ counts,
                                                int* __restrict__ offs,
                                                int* __restrict__ bsum) {
    __shared__ int wsum[4];
    int t = threadIdx.x, lane = t & 63, wid = t >> 6;
    int g = blockIdx.x * 256 + t;
    int v = counts[g];
    int x = v;
#pragma unroll
    for (int off = 1; off < 64; off <<= 1) {
        int u = __shfl_up(x, off);
        if (lane >= off) x += u;
    }
    if (lane == 63) wsum[wid] = x;
    __syncthreads();
    int base = 0;
    if (wid > 0) base += wsum[0];
    if (wid > 1) base += wsum[1];
    if (wid > 2) base += wsum[2];
    offs[g] = base + x - v;                       // block-exclusive prefix
    if (t == 255) bsum[blockIdx.x] = base + x;    // block total
}

// Position-indexed emit + pad, fully coalesced (proven structure: local
// level-2 scan + serial search hidden under 538-block parallelism).
// d2 recomputed from coords (system window 12KB -> L1-resident); u16 records.
// Out layout: [0)src [MP)dst [2MP)dst [3MP)src [4MP)d12 [5MP)d12 [6MP]npairs
__global__ __launch_bounds__(1024) void k_emit(const float* __restrict__ coords,
                                               const int* __restrict__ offs,
                                               const int* __restrict__ bsum,
                                               const unsigned short* __restrict__ qbuf,
                                               float* __restrict__ out) {
    __shared__ int bpre[256];
    __shared__ int lgoff[NROWS + 1];
    __shared__ int sh_r0, sh_tot;
    int t = threadIdx.x;
    int v = 0;
    if (t < 256) {
        v = (t < SCAN_BLOCKS) ? bsum[t] : 0;
        bpre[t] = v;
    }
    __syncthreads();
    for (int off = 1; off < 256; off <<= 1) {
        int u = 0;
        if (t < 256 && t >= off) u = bpre[t - off];
        __syncthreads();
        if (t < 256) bpre[t] += u;
        __syncthreads();
    }
    int incl = (t < 256) ? bpre[t] : 0;
    __syncthreads();
    if (t < 256) bpre[t] = incl - v;                 // exclusive prefix
    if (t == 255) sh_tot = incl;                     // grand total
    __syncthreads();
    int total = sh_tot;

    int p0 = blockIdx.x * POSB;
    if (t == 0) {
        int lo = 0, hi = NTOT;                       // largest r: goff(r) <= p0
        while (lo < hi) {
            int mid = (lo + hi + 1) >> 1;
            int g = (mid < NTOT) ? offs[mid] + bpre[mid >> 8] : total;
            if (g <= p0) lo = mid; else hi = mid - 1;
        }
        sh_r0 = lo;
    }
    __syncthreads();
    int r0 = sh_r0;
    if (t <= NROWS) {
        int r = r0 + t;
        lgoff[t] = (r < NTOT) ? offs[r] + bpre[r >> 8] : total;
    }
    __syncthreads();

    if (blockIdx.x == 0 && t == 0) out[6 * MP] = (float)total;  // npairs
    int valid = total < MP ? total : MP;

    int p4 = p0 + t * 4;
    if (p4 >= MP) return;
    int k = 0;
    for (int step = 256; step; step >>= 1) {
        int nk = k + step;
        if (nk <= NROWS - 1 && lgoff[nk] <= p4) k = nk;
    }
    float fs[4], fd[4], dd[4];
#pragma unroll
    for (int e = 0; e < 4; e++) {
        int p = p4 + e;
        if (p < valid) {
            while (k < NROWS - 1 && lgoff[k + 1] <= p) k++;
            int row = r0 + k;
            int local = p - lgoff[k];
            if (local > CAP - 1) local = CAP - 1;    // count>CAP guard (P~0)
            int dj = qbuf[(size_t)row * CAP + local];
            int col = row + dj;
            const float* cr = coords + 3 * row;
            const float* cj = coords + 3 * col;
            fs[e] = (float)row;
            fd[e] = (float)col;
            dd[e] = dist2f(cr[0], cr[1], cr[2], cj[0], cj[1], cj[2]);
        } else {
            fs[e] = PADV; fd[e] = PADV; dd[e] = CUT2;
        }
    }
    if (p4 + 4 <= MP) {
        float4 vs = {fs[0], fs[1], fs[2], fs[3]};
        float4 vd = {fd[0], fd[1], fd[2], fd[3]};
        float4 vv = {dd[0], dd[1], dd[2], dd[3]};
        *(float4*)(out + p4)          = vs;
        *(float4*)(out + MP + p4)     = vd;
        *(float4*)(out + 2 * MP + p4) = vd;
        *(float4*)(out + 3 * MP + p4) = vs;
        *(float4*)(out + 4 * MP + p4) = vv;
        *(float4*)(out + 5 * MP + p4) = vv;
    } else {
#pragma unroll
        for (int e = 0; e < 4; e++) {
            int p = p4 + e;
            if (p < MP) {
                out[p]          = fs[e];
                out[MP + p]     = fd[e];
                out[2 * MP + p] = fd[e];
                out[3 * MP + p] = fs[e];
                out[4 * MP + p] = dd[e];
                out[5 * MP + p] = dd[e];
            }
        }
    }
}

extern "C" void kernel_launch(void* const* d_in, const int* in_sizes, int n_in,
                              void* d_out, int out_size, void* d_ws, size_t ws_size,
                              hipStream_t stream) {
    const float* coords = (const float*)d_in[0];
    float* out = (float*)d_out;

    // Workspace: counts[64000] | offs[64000] | bsum[256] | qbuf u16 (13.3MB)
    int*            counts = (int*)d_ws;
    int*            offs   = counts + NTOT;
    int*            bsum   = offs + NTOT;
    unsigned short* qbuf   = (unsigned short*)(bsum + 256);

    int emit_blocks = (MP + POSB - 1) / POSB;        // 538
    k_eval<<<EB, 1024, 0, stream>>>(coords, counts, qbuf);
    k_scan_a<<<SCAN_BLOCKS, 256, 0, stream>>>(counts, offs, bsum);
    k_emit<<<emit_blocks, 1024, 0, stream>>>(coords, offs, bsum, qbuf, out);
}